// Round 6
// baseline (302.540 us; speedup 1.0000x reference)
//
#include <hip/hip_runtime.h>
#include <hip/hip_fp16.h>

// Problem constants (match reference)
#define N_NODES 100000
#define N_EDGES 3200000
#define IN_F    128
#define HID     3
#define OUT_F   4

// Bucketed partition parameters
#define BSHIFT  7
#define BSIZE   128                                  // dest nodes per bucket
#define NBUCK   ((N_NODES + BSIZE - 1) / BSIZE)      // 782
#define NBLKA   512                                  // partition blocks
#define EPB     ((N_EDGES + NBLKA - 1) / NBLKA)      // 6250 edges per block
#define NH      (NBUCK * NBLKA)                      // 400384 hist entries

#define SCAN_ITEMS 16
#define SCAN_BLOCK 256
#define SCAN_PER_BLOCK (SCAN_ITEMS * SCAN_BLOCK)                 // 4096
#define NS1 ((NH + SCAN_PER_BLOCK - 1) / SCAN_PER_BLOCK)         // 98

// LDS accumulator replication (anti-serialization)
#define NREP    4
#define RSTRIDE 392     // floats; 392%32==8 -> replica r shifts banks by 8
#define CSTRIDE 136     // ints for degree counters

// native vector type usable with __builtin_nontemporal_load
typedef float f32x4 __attribute__((ext_vector_type(4)));

// d_ws layout (bytes):
//   histG  : NH ints              (1.6 MB)  bucket-major [bucket][block]
//   packed : N_EDGES ints         (12.8 MB) bucket-sorted (row<<7 | col&127)
//   xw     : N_NODES*3 floats     (1.2 MB)
//   tab    : N_NODES uint2        (0.8 MB)  {h(xw0*d),h(xw1*d),h(xw2*d),h(d)}
//   bsum   : NS1 ints

// ---------------- xw = x @ W : 2 nodes per 64-lane wave, float4 loads ----
__global__ void xw_kernel(const float* __restrict__ x,
                          const float* __restrict__ W,
                          float* __restrict__ xw) {
    int wave = threadIdx.x >> 6;        // 4 waves / block
    int lane = threadIdx.x & 63;
    int half = lane >> 5;               // which node within the wave
    int l    = lane & 31;               // 32 lanes x float4 = 128 elems
    int node = blockIdx.x * 8 + wave * 2 + half;
    if (node >= N_NODES) return;

    f32x4 xv = __builtin_nontemporal_load(
        reinterpret_cast<const f32x4*>(x + (size_t)node * IN_F + l * 4));
    const float* w = W + l * 4 * HID;   // rows 4l..4l+3 of W[128][3]
    float s0 = xv.x * w[0] + xv.y * w[3] + xv.z * w[6] + xv.w * w[9];
    float s1 = xv.x * w[1] + xv.y * w[4] + xv.z * w[7] + xv.w * w[10];
    float s2 = xv.x * w[2] + xv.y * w[5] + xv.z * w[8] + xv.w * w[11];
    #pragma unroll
    for (int off = 16; off > 0; off >>= 1) {
        s0 += __shfl_down(s0, off, 32);
        s1 += __shfl_down(s1, off, 32);
        s2 += __shfl_down(s2, off, 32);
    }
    if (l == 0) {
        xw[node * 3 + 0] = s0;
        xw[node * 3 + 1] = s1;
        xw[node * 3 + 2] = s2;
    }
}

// ---------- pass A: per-block LDS histogram over coarse buckets ----------
__global__ void histA_kernel(const int* __restrict__ col, int* __restrict__ histG) {
    __shared__ int hist[NBUCK];
    int tid = threadIdx.x, blk = blockIdx.x;
    for (int i = tid; i < NBUCK; i += 256) hist[i] = 0;
    __syncthreads();
    int start = blk * EPB, end = min(start + EPB, N_EDGES);
    for (int e = start + tid; e < end; e += 256)
        atomicAdd(&hist[__builtin_nontemporal_load(&col[e]) >> BSHIFT], 1);
    __syncthreads();
    for (int i = tid; i < NBUCK; i += 256)
        histG[i * NBLKA + blk] = hist[i];   // bucket-major
}

// ---------------- exclusive scan over histG[NH] --------------------------
__global__ void scan1_kernel(int* __restrict__ data, int* __restrict__ bsum) {
    __shared__ int s[SCAN_BLOCK];
    int tid = threadIdx.x;
    int base = blockIdx.x * SCAN_PER_BLOCK + tid * SCAN_ITEMS;
    int v[SCAN_ITEMS];
    int tsum = 0;
    #pragma unroll
    for (int j = 0; j < SCAN_ITEMS; ++j) {
        v[j] = (base + j < NH) ? data[base + j] : 0;
        tsum += v[j];
    }
    s[tid] = tsum;
    __syncthreads();
    for (int off = 1; off < SCAN_BLOCK; off <<= 1) {
        int t = (tid >= off) ? s[tid - off] : 0;
        __syncthreads();
        s[tid] += t;
        __syncthreads();
    }
    int run = s[tid] - tsum;
    #pragma unroll
    for (int j = 0; j < SCAN_ITEMS; ++j) {
        int t = v[j];
        if (base + j < NH) data[base + j] = run;
        run += t;
    }
    if (tid == SCAN_BLOCK - 1) bsum[blockIdx.x] = s[SCAN_BLOCK - 1];
}

__global__ void scan2_kernel(int* __restrict__ bsum) {
    __shared__ int s[SCAN_BLOCK];
    int tid = threadIdx.x;
    int v = (tid < NS1) ? bsum[tid] : 0;
    s[tid] = v;
    __syncthreads();
    for (int off = 1; off < SCAN_BLOCK; off <<= 1) {
        int t = (tid >= off) ? s[tid - off] : 0;
        __syncthreads();
        s[tid] += t;
        __syncthreads();
    }
    if (tid < NS1) bsum[tid] = s[tid] - v;
}

__global__ void scan3_kernel(int* __restrict__ data, const int* __restrict__ bsum) {
    int i = blockIdx.x * blockDim.x + threadIdx.x;
    if (i < NH) data[i] += bsum[i / SCAN_PER_BLOCK];
}

// ---------- pass B: scatter packed edges into bucket-sorted order --------
__global__ void fillB_kernel(const int* __restrict__ row,
                             const int* __restrict__ col,
                             const int* __restrict__ histG,
                             int* __restrict__ packed) {
    __shared__ int offs[NBUCK];
    int tid = threadIdx.x, blk = blockIdx.x;
    for (int i = tid; i < NBUCK; i += 256) offs[i] = histG[i * NBLKA + blk];
    __syncthreads();
    int start = blk * EPB, end = min(start + EPB, N_EDGES);
    for (int e = start + tid; e < end; e += 256) {
        int c = __builtin_nontemporal_load(&col[e]);
        int r = __builtin_nontemporal_load(&row[e]);
        int b = c >> BSHIFT;
        int pos = atomicAdd(&offs[b], 1);   // LDS atomic
        __builtin_nontemporal_store((r << BSHIFT) | (c & (BSIZE - 1)), &packed[pos]);
    }
}

// ---------- C1: per-dest degree + fused fp16 table: {xw*d, d} ------------
__global__ __launch_bounds__(512, 8) void degC_kernel(const int* __restrict__ histG,
                                                      const int* __restrict__ packed,
                                                      const float* __restrict__ xw,
                                                      uint2* __restrict__ tab) {
    __shared__ int cnt[NREP * CSTRIDE];
    int tid = threadIdx.x, b = blockIdx.x;
    int rep = tid & (NREP - 1);
    for (int i = tid; i < NREP * CSTRIDE; i += 512) cnt[i] = 0;
    __syncthreads();
    int start = histG[b * NBLKA];
    int end   = (b + 1 < NBUCK) ? histG[(b + 1) * NBLKA] : N_EDGES;
    int len   = end - start;
    int nfull = len & ~(4 * 512 - 1);
    for (int off = tid; off < nfull; off += 2048) {
        int p0 = __builtin_nontemporal_load(&packed[start + off]);
        int p1 = __builtin_nontemporal_load(&packed[start + off + 512]);
        int p2 = __builtin_nontemporal_load(&packed[start + off + 1024]);
        int p3 = __builtin_nontemporal_load(&packed[start + off + 1536]);
        atomicAdd(&cnt[rep * CSTRIDE + (p0 & (BSIZE - 1))], 1);
        atomicAdd(&cnt[rep * CSTRIDE + (p1 & (BSIZE - 1))], 1);
        atomicAdd(&cnt[rep * CSTRIDE + (p2 & (BSIZE - 1))], 1);
        atomicAdd(&cnt[rep * CSTRIDE + (p3 & (BSIZE - 1))], 1);
    }
    for (int off = nfull + tid; off < len; off += 512)
        atomicAdd(&cnt[rep * CSTRIDE + (__builtin_nontemporal_load(&packed[start + off]) & (BSIZE - 1))], 1);
    __syncthreads();
    if (tid < BSIZE) {
        int node = b * BSIZE + tid;
        if (node < N_NODES) {
            int c = cnt[0 * CSTRIDE + tid] + cnt[1 * CSTRIDE + tid]
                  + cnt[2 * CSTRIDE + tid] + cnt[3 * CSTRIDE + tid];
            float d = rsqrtf((float)(c + 1));   // +1 self loop
            __half2 lo = __floats2half2_rn(xw[node * 3 + 0] * d, xw[node * 3 + 1] * d);
            __half2 hi = __floats2half2_rn(xw[node * 3 + 2] * d, d);
            uint2 u;
            u.x = *reinterpret_cast<unsigned int*>(&lo);
            u.y = *reinterpret_cast<unsigned int*>(&hi);
            tab[node] = u;
        }
    }
}

__device__ inline void unpack4(uint2 u, float& a, float& b, float& c, float& d) {
    __half2 lo = *reinterpret_cast<__half2*>(&u.x);
    __half2 hi = *reinterpret_cast<__half2*>(&u.y);
    float2 f0 = __half22float2(lo);
    float2 f1 = __half22float2(hi);
    a = f0.x; b = f0.y; c = f1.x; d = f1.y;
}

// ---------- C2: bucket aggregation in replicated LDS + fused epilogue ----
__global__ __launch_bounds__(512, 8) void aggC_kernel(const int* __restrict__ histG,
                                                      const int* __restrict__ packed,
                                                      const uint2* __restrict__ tab,
                                                      const float* __restrict__ bb,
                                                      const float* __restrict__ Wout,
                                                      const float* __restrict__ bout,
                                                      float* __restrict__ out) {
    __shared__ float acc[NREP * RSTRIDE];
    int tid = threadIdx.x, b = blockIdx.x;
    int rep = tid & (NREP - 1);
    float* myacc = acc + rep * RSTRIDE;
    for (int i = tid; i < NREP * RSTRIDE; i += 512) acc[i] = 0.f;
    __syncthreads();
    int start = histG[b * NBLKA];
    int end   = (b + 1 < NBUCK) ? histG[(b + 1) * NBLKA] : N_EDGES;
    int len   = end - start;
    int nfull = len & ~(4 * 512 - 1);
    for (int off = tid; off < nfull; off += 2048) {
        int p0 = __builtin_nontemporal_load(&packed[start + off]);
        int p1 = __builtin_nontemporal_load(&packed[start + off + 512]);
        int p2 = __builtin_nontemporal_load(&packed[start + off + 1024]);
        int p3 = __builtin_nontemporal_load(&packed[start + off + 1536]);
        uint2 u0 = tab[p0 >> BSHIFT];
        uint2 u1 = tab[p1 >> BSHIFT];
        uint2 u2 = tab[p2 >> BSHIFT];
        uint2 u3 = tab[p3 >> BSHIFT];
        float a0, b0, c0, d0, a1, b1, c1, d1, a2, b2, c2, d2, a3, b3, c3, d3;
        unpack4(u0, a0, b0, c0, d0);
        unpack4(u1, a1, b1, c1, d1);
        unpack4(u2, a2, b2, c2, d2);
        unpack4(u3, a3, b3, c3, d3);
        int i0 = (p0 & (BSIZE - 1)) * 3, i1 = (p1 & (BSIZE - 1)) * 3;
        int i2 = (p2 & (BSIZE - 1)) * 3, i3 = (p3 & (BSIZE - 1)) * 3;
        atomicAdd(&myacc[i0 + 0], a0); atomicAdd(&myacc[i0 + 1], b0); atomicAdd(&myacc[i0 + 2], c0);
        atomicAdd(&myacc[i1 + 0], a1); atomicAdd(&myacc[i1 + 1], b1); atomicAdd(&myacc[i1 + 2], c1);
        atomicAdd(&myacc[i2 + 0], a2); atomicAdd(&myacc[i2 + 1], b2); atomicAdd(&myacc[i2 + 2], c2);
        atomicAdd(&myacc[i3 + 0], a3); atomicAdd(&myacc[i3 + 1], b3); atomicAdd(&myacc[i3 + 2], c3);
    }
    for (int off = nfull + tid; off < len; off += 512) {
        int p = __builtin_nontemporal_load(&packed[start + off]);
        uint2 u = tab[p >> BSHIFT];
        float a, bq, c, d;
        unpack4(u, a, bq, c, d);
        int i = (p & (BSIZE - 1)) * 3;
        atomicAdd(&myacc[i + 0], a);
        atomicAdd(&myacc[i + 1], bq);
        atomicAdd(&myacc[i + 2], c);
    }
    __syncthreads();
    if (tid < BSIZE) {
        int node = b * BSIZE + tid;
        if (node < N_NODES) {
            float sx, sy, sz, di;
            unpack4(tab[node], sx, sy, sz, di);
            float g0 = sx, g1 = sy, g2 = sz;
            #pragma unroll
            for (int rr = 0; rr < NREP; ++rr) {
                g0 += acc[rr * RSTRIDE + tid * 3 + 0];
                g1 += acc[rr * RSTRIDE + tid * 3 + 1];
                g2 += acc[rr * RSTRIDE + tid * 3 + 2];
            }
            float h0 = fmaxf(g0 * di + bb[0], 0.f);
            float h1 = fmaxf(g1 * di + bb[1], 0.f);
            float h2 = fmaxf(g2 * di + bb[2], 0.f);
            out[node * 3 + 0] = h0;
            out[node * 3 + 1] = h1;
            out[node * 3 + 2] = h2;
            float* z = out + (size_t)N_NODES * 3;
            #pragma unroll
            for (int k = 0; k < 4; ++k) {
                z[node * 4 + k] = bout[k] + h0 * Wout[0 * 4 + k]
                                          + h1 * Wout[1 * 4 + k]
                                          + h2 * Wout[2 * 4 + k];
            }
        }
    }
}

extern "C" void kernel_launch(void* const* d_in, const int* in_sizes, int n_in,
                              void* d_out, int out_size, void* d_ws, size_t ws_size,
                              hipStream_t stream) {
    const float* x    = (const float*)d_in[0];
    const int*   ei   = (const int*)d_in[1];   // [2, N_EDGES]: row then col
    const float* W    = (const float*)d_in[2];
    const float* b    = (const float*)d_in[3];
    const float* Wout = (const float*)d_in[4];
    const float* bout = (const float*)d_in[5];
    float* out = (float*)d_out;

    char* wsb = (char*)d_ws;
    int*   histG  = (int*)(wsb);
    int*   packed = (int*)(wsb + (size_t)NH * 4);
    float* xw     = (float*)(wsb + (size_t)NH * 4 + (size_t)N_EDGES * 4);
    uint2* tab    = (uint2*)((char*)xw + (size_t)N_NODES * 3 * 4);
    int*   bsum   = (int*)((char*)tab + (size_t)N_NODES * 8);

    const int* row = ei;
    const int* col = ei + N_EDGES;

    const int B = 256;
    int gridX  = (N_NODES + 7) / 8;
    int gridS3 = (NH + B - 1) / B;

    xw_kernel<<<gridX, B, 0, stream>>>(x, W, xw);
    histA_kernel<<<NBLKA, B, 0, stream>>>(col, histG);
    scan1_kernel<<<NS1, SCAN_BLOCK, 0, stream>>>(histG, bsum);
    scan2_kernel<<<1, SCAN_BLOCK, 0, stream>>>(bsum);
    scan3_kernel<<<gridS3, B, 0, stream>>>(histG, bsum);
    fillB_kernel<<<NBLKA, B, 0, stream>>>(row, col, histG, packed);
    degC_kernel<<<NBUCK, 512, 0, stream>>>(histG, packed, xw, tab);
    aggC_kernel<<<NBUCK, 512, 0, stream>>>(histG, packed, tab, b, Wout, bout, out);
}

// Round 7
// 267.514 us; speedup vs baseline: 1.1309x; 1.1309x over previous
//
#include <hip/hip_runtime.h>
#include <hip/hip_fp16.h>

// Problem constants (match reference)
#define N_NODES 100000
#define N_EDGES 3200000
#define IN_F    128
#define HID     3
#define OUT_F   4

// Bucketed partition parameters
#define BSHIFT  7
#define BSIZE   128                                  // dest nodes per bucket
#define NBUCK   ((N_NODES + BSIZE - 1) / BSIZE)      // 782
#define NBLKA   512                                  // partition blocks
#define EPB     ((N_EDGES + NBLKA - 1) / NBLKA)      // 6250 edges per block
#define NH      (NBUCK * NBLKA)                      // 400384 hist entries

#define SCAN_ITEMS 16
#define SCAN_BLOCK 256
#define SCAN_PER_BLOCK (SCAN_ITEMS * SCAN_BLOCK)                 // 4096
#define NS1 ((NH + SCAN_PER_BLOCK - 1) / SCAN_PER_BLOCK)         // 98

// LDS accumulator replication (anti-serialization)
#define NREP    4
#define RSTRIDE 392     // floats; 392%32==8 -> replica r shifts banks by 8
#define CSTRIDE 136     // ints for degree counters

// native vector type usable with __builtin_nontemporal_load
typedef float f32x4 __attribute__((ext_vector_type(4)));

// d_ws layout (bytes):
//   histG  : NH ints              (1.6 MB)  bucket-major [bucket][block]
//   packed : N_EDGES ints         (12.8 MB) bucket-sorted (row<<7 | col&127)
//   xw     : N_NODES*3 floats     (1.2 MB)
//   tab    : N_NODES uint2        (0.8 MB)  {h(xw0*d),h(xw1*d),h(xw2*d),h(d)}
//   bsum   : NS1 ints

// ---------------- xw = x @ W : 2 nodes per 64-lane wave, float4 loads ----
__global__ void xw_kernel(const float* __restrict__ x,
                          const float* __restrict__ W,
                          float* __restrict__ xw) {
    int wave = threadIdx.x >> 6;        // 4 waves / block
    int lane = threadIdx.x & 63;
    int half = lane >> 5;               // which node within the wave
    int l    = lane & 31;               // 32 lanes x float4 = 128 elems
    int node = blockIdx.x * 8 + wave * 2 + half;
    if (node >= N_NODES) return;

    f32x4 xv = __builtin_nontemporal_load(
        reinterpret_cast<const f32x4*>(x + (size_t)node * IN_F + l * 4));
    const float* w = W + l * 4 * HID;   // rows 4l..4l+3 of W[128][3]
    float s0 = xv.x * w[0] + xv.y * w[3] + xv.z * w[6] + xv.w * w[9];
    float s1 = xv.x * w[1] + xv.y * w[4] + xv.z * w[7] + xv.w * w[10];
    float s2 = xv.x * w[2] + xv.y * w[5] + xv.z * w[8] + xv.w * w[11];
    #pragma unroll
    for (int off = 16; off > 0; off >>= 1) {
        s0 += __shfl_down(s0, off, 32);
        s1 += __shfl_down(s1, off, 32);
        s2 += __shfl_down(s2, off, 32);
    }
    if (l == 0) {
        xw[node * 3 + 0] = s0;
        xw[node * 3 + 1] = s1;
        xw[node * 3 + 2] = s2;
    }
}

// ---------- pass A: per-block LDS histogram over coarse buckets ----------
__global__ __launch_bounds__(512) void histA_kernel(const int* __restrict__ col,
                                                    int* __restrict__ histG) {
    __shared__ int hist[NBUCK];
    int tid = threadIdx.x, blk = blockIdx.x;
    for (int i = tid; i < NBUCK; i += 512) hist[i] = 0;
    __syncthreads();
    int start = blk * EPB, end = min(start + EPB, N_EDGES);
    for (int e = start + tid; e < end; e += 512)
        atomicAdd(&hist[__builtin_nontemporal_load(&col[e]) >> BSHIFT], 1);
    __syncthreads();
    for (int i = tid; i < NBUCK; i += 512)
        histG[i * NBLKA + blk] = hist[i];   // bucket-major
}

// ---------------- exclusive scan over histG[NH] --------------------------
__global__ void scan1_kernel(int* __restrict__ data, int* __restrict__ bsum) {
    __shared__ int s[SCAN_BLOCK];
    int tid = threadIdx.x;
    int base = blockIdx.x * SCAN_PER_BLOCK + tid * SCAN_ITEMS;
    int v[SCAN_ITEMS];
    int tsum = 0;
    #pragma unroll
    for (int j = 0; j < SCAN_ITEMS; ++j) {
        v[j] = (base + j < NH) ? data[base + j] : 0;
        tsum += v[j];
    }
    s[tid] = tsum;
    __syncthreads();
    for (int off = 1; off < SCAN_BLOCK; off <<= 1) {
        int t = (tid >= off) ? s[tid - off] : 0;
        __syncthreads();
        s[tid] += t;
        __syncthreads();
    }
    int run = s[tid] - tsum;
    #pragma unroll
    for (int j = 0; j < SCAN_ITEMS; ++j) {
        int t = v[j];
        if (base + j < NH) data[base + j] = run;
        run += t;
    }
    if (tid == SCAN_BLOCK - 1) bsum[blockIdx.x] = s[SCAN_BLOCK - 1];
}

__global__ void scan2_kernel(int* __restrict__ bsum) {
    __shared__ int s[SCAN_BLOCK];
    int tid = threadIdx.x;
    int v = (tid < NS1) ? bsum[tid] : 0;
    s[tid] = v;
    __syncthreads();
    for (int off = 1; off < SCAN_BLOCK; off <<= 1) {
        int t = (tid >= off) ? s[tid - off] : 0;
        __syncthreads();
        s[tid] += t;
        __syncthreads();
    }
    if (tid < NS1) bsum[tid] = s[tid] - v;
}

__global__ void scan3_kernel(int* __restrict__ data, const int* __restrict__ bsum) {
    int i = blockIdx.x * blockDim.x + threadIdx.x;
    if (i < NH) data[i] += bsum[i / SCAN_PER_BLOCK];
}

// ---------- pass B: scatter packed edges into bucket-sorted order --------
__global__ __launch_bounds__(512) void fillB_kernel(const int* __restrict__ row,
                                                    const int* __restrict__ col,
                                                    const int* __restrict__ histG,
                                                    int* __restrict__ packed) {
    __shared__ int offs[NBUCK];
    int tid = threadIdx.x, blk = blockIdx.x;
    for (int i = tid; i < NBUCK; i += 512) offs[i] = histG[i * NBLKA + blk];
    __syncthreads();
    int start = blk * EPB, end = min(start + EPB, N_EDGES);
    for (int e = start + tid; e < end; e += 512) {
        int c = __builtin_nontemporal_load(&col[e]);
        int r = __builtin_nontemporal_load(&row[e]);
        int b = c >> BSHIFT;
        int pos = atomicAdd(&offs[b], 1);   // LDS atomic
        packed[pos] = (r << BSHIFT) | (c & (BSIZE - 1));   // cached store: L2 merges runs
    }
}

// ---------- C1: per-dest degree + fused fp16 table: {xw*d, d} ------------
__global__ __launch_bounds__(512, 8) void degC_kernel(const int* __restrict__ histG,
                                                      const int* __restrict__ packed,
                                                      const float* __restrict__ xw,
                                                      uint2* __restrict__ tab) {
    __shared__ int cnt[NREP * CSTRIDE];
    int tid = threadIdx.x, b = blockIdx.x;
    int rep = tid & (NREP - 1);
    for (int i = tid; i < NREP * CSTRIDE; i += 512) cnt[i] = 0;
    __syncthreads();
    int start = histG[b * NBLKA];
    int end   = (b + 1 < NBUCK) ? histG[(b + 1) * NBLKA] : N_EDGES;
    int len   = end - start;
    int nfull = len & ~(4 * 512 - 1);
    for (int off = tid; off < nfull; off += 2048) {
        int p0 = __builtin_nontemporal_load(&packed[start + off]);
        int p1 = __builtin_nontemporal_load(&packed[start + off + 512]);
        int p2 = __builtin_nontemporal_load(&packed[start + off + 1024]);
        int p3 = __builtin_nontemporal_load(&packed[start + off + 1536]);
        atomicAdd(&cnt[rep * CSTRIDE + (p0 & (BSIZE - 1))], 1);
        atomicAdd(&cnt[rep * CSTRIDE + (p1 & (BSIZE - 1))], 1);
        atomicAdd(&cnt[rep * CSTRIDE + (p2 & (BSIZE - 1))], 1);
        atomicAdd(&cnt[rep * CSTRIDE + (p3 & (BSIZE - 1))], 1);
    }
    for (int off = nfull + tid; off < len; off += 512)
        atomicAdd(&cnt[rep * CSTRIDE + (__builtin_nontemporal_load(&packed[start + off]) & (BSIZE - 1))], 1);
    __syncthreads();
    if (tid < BSIZE) {
        int node = b * BSIZE + tid;
        if (node < N_NODES) {
            int c = cnt[0 * CSTRIDE + tid] + cnt[1 * CSTRIDE + tid]
                  + cnt[2 * CSTRIDE + tid] + cnt[3 * CSTRIDE + tid];
            float d = rsqrtf((float)(c + 1));   // +1 self loop
            __half2 lo = __floats2half2_rn(xw[node * 3 + 0] * d, xw[node * 3 + 1] * d);
            __half2 hi = __floats2half2_rn(xw[node * 3 + 2] * d, d);
            uint2 u;
            u.x = *reinterpret_cast<unsigned int*>(&lo);
            u.y = *reinterpret_cast<unsigned int*>(&hi);
            tab[node] = u;
        }
    }
}

__device__ inline void unpack4(uint2 u, float& a, float& b, float& c, float& d) {
    __half2 lo = *reinterpret_cast<__half2*>(&u.x);
    __half2 hi = *reinterpret_cast<__half2*>(&u.y);
    float2 f0 = __half22float2(lo);
    float2 f1 = __half22float2(hi);
    a = f0.x; b = f0.y; c = f1.x; d = f1.y;
}

// ---------- C2: bucket aggregation in replicated LDS + fused epilogue ----
__global__ __launch_bounds__(512, 8) void aggC_kernel(const int* __restrict__ histG,
                                                      const int* __restrict__ packed,
                                                      const uint2* __restrict__ tab,
                                                      const float* __restrict__ bb,
                                                      const float* __restrict__ Wout,
                                                      const float* __restrict__ bout,
                                                      float* __restrict__ out) {
    __shared__ float acc[NREP * RSTRIDE];
    int tid = threadIdx.x, b = blockIdx.x;
    int rep = tid & (NREP - 1);
    float* myacc = acc + rep * RSTRIDE;
    for (int i = tid; i < NREP * RSTRIDE; i += 512) acc[i] = 0.f;
    __syncthreads();
    int start = histG[b * NBLKA];
    int end   = (b + 1 < NBUCK) ? histG[(b + 1) * NBLKA] : N_EDGES;
    int len   = end - start;
    int nfull = len & ~(4 * 512 - 1);
    for (int off = tid; off < nfull; off += 2048) {
        int p0 = __builtin_nontemporal_load(&packed[start + off]);
        int p1 = __builtin_nontemporal_load(&packed[start + off + 512]);
        int p2 = __builtin_nontemporal_load(&packed[start + off + 1024]);
        int p3 = __builtin_nontemporal_load(&packed[start + off + 1536]);
        uint2 u0 = tab[p0 >> BSHIFT];
        uint2 u1 = tab[p1 >> BSHIFT];
        uint2 u2 = tab[p2 >> BSHIFT];
        uint2 u3 = tab[p3 >> BSHIFT];
        float a0, b0, c0, d0, a1, b1, c1, d1, a2, b2, c2, d2, a3, b3, c3, d3;
        unpack4(u0, a0, b0, c0, d0);
        unpack4(u1, a1, b1, c1, d1);
        unpack4(u2, a2, b2, c2, d2);
        unpack4(u3, a3, b3, c3, d3);
        int i0 = (p0 & (BSIZE - 1)) * 3, i1 = (p1 & (BSIZE - 1)) * 3;
        int i2 = (p2 & (BSIZE - 1)) * 3, i3 = (p3 & (BSIZE - 1)) * 3;
        atomicAdd(&myacc[i0 + 0], a0); atomicAdd(&myacc[i0 + 1], b0); atomicAdd(&myacc[i0 + 2], c0);
        atomicAdd(&myacc[i1 + 0], a1); atomicAdd(&myacc[i1 + 1], b1); atomicAdd(&myacc[i1 + 2], c1);
        atomicAdd(&myacc[i2 + 0], a2); atomicAdd(&myacc[i2 + 1], b2); atomicAdd(&myacc[i2 + 2], c2);
        atomicAdd(&myacc[i3 + 0], a3); atomicAdd(&myacc[i3 + 1], b3); atomicAdd(&myacc[i3 + 2], c3);
    }
    for (int off = nfull + tid; off < len; off += 512) {
        int p = __builtin_nontemporal_load(&packed[start + off]);
        uint2 u = tab[p >> BSHIFT];
        float a, bq, c, d;
        unpack4(u, a, bq, c, d);
        int i = (p & (BSIZE - 1)) * 3;
        atomicAdd(&myacc[i + 0], a);
        atomicAdd(&myacc[i + 1], bq);
        atomicAdd(&myacc[i + 2], c);
    }
    __syncthreads();
    if (tid < BSIZE) {
        int node = b * BSIZE + tid;
        if (node < N_NODES) {
            float sx, sy, sz, di;
            unpack4(tab[node], sx, sy, sz, di);
            float g0 = sx, g1 = sy, g2 = sz;
            #pragma unroll
            for (int rr = 0; rr < NREP; ++rr) {
                g0 += acc[rr * RSTRIDE + tid * 3 + 0];
                g1 += acc[rr * RSTRIDE + tid * 3 + 1];
                g2 += acc[rr * RSTRIDE + tid * 3 + 2];
            }
            float h0 = fmaxf(g0 * di + bb[0], 0.f);
            float h1 = fmaxf(g1 * di + bb[1], 0.f);
            float h2 = fmaxf(g2 * di + bb[2], 0.f);
            out[node * 3 + 0] = h0;
            out[node * 3 + 1] = h1;
            out[node * 3 + 2] = h2;
            float* z = out + (size_t)N_NODES * 3;
            #pragma unroll
            for (int k = 0; k < 4; ++k) {
                z[node * 4 + k] = bout[k] + h0 * Wout[0 * 4 + k]
                                          + h1 * Wout[1 * 4 + k]
                                          + h2 * Wout[2 * 4 + k];
            }
        }
    }
}

extern "C" void kernel_launch(void* const* d_in, const int* in_sizes, int n_in,
                              void* d_out, int out_size, void* d_ws, size_t ws_size,
                              hipStream_t stream) {
    const float* x    = (const float*)d_in[0];
    const int*   ei   = (const int*)d_in[1];   // [2, N_EDGES]: row then col
    const float* W    = (const float*)d_in[2];
    const float* b    = (const float*)d_in[3];
    const float* Wout = (const float*)d_in[4];
    const float* bout = (const float*)d_in[5];
    float* out = (float*)d_out;

    char* wsb = (char*)d_ws;
    int*   histG  = (int*)(wsb);
    int*   packed = (int*)(wsb + (size_t)NH * 4);
    float* xw     = (float*)(wsb + (size_t)NH * 4 + (size_t)N_EDGES * 4);
    uint2* tab    = (uint2*)((char*)xw + (size_t)N_NODES * 3 * 4);
    int*   bsum   = (int*)((char*)tab + (size_t)N_NODES * 8);

    const int* row = ei;
    const int* col = ei + N_EDGES;

    const int B = 256;
    int gridX  = (N_NODES + 7) / 8;
    int gridS3 = (NH + B - 1) / B;

    xw_kernel<<<gridX, B, 0, stream>>>(x, W, xw);
    histA_kernel<<<NBLKA, 512, 0, stream>>>(col, histG);
    scan1_kernel<<<NS1, SCAN_BLOCK, 0, stream>>>(histG, bsum);
    scan2_kernel<<<1, SCAN_BLOCK, 0, stream>>>(bsum);
    scan3_kernel<<<gridS3, B, 0, stream>>>(histG, bsum);
    fillB_kernel<<<NBLKA, 512, 0, stream>>>(row, col, histG, packed);
    degC_kernel<<<NBUCK, 512, 0, stream>>>(histG, packed, xw, tab);
    aggC_kernel<<<NBUCK, 512, 0, stream>>>(histG, packed, tab, b, Wout, bout, out);
}